// Round 6
// baseline (36.388 us; speedup 1.0000x reference)
//
#include <hip/hip_runtime.h>
#include <hip/hip_bf16.h>

// Y-gate on qubit INDEX=12 of a D=2, N=2^24 state vector.
// Partner index: j = k ^ 2048 (bit 11 = target-qubit bit).
// Output: bf16, interleaved pairs, 2^25 values total.
// Harness conventions (established empirically, rounds 0-5; r5 PASSED):
//   even slot[k] = s*A[j], odd slot[k] = -s*B[j]  with A=d_in[0], B=d_in[1],
//   s = -1 when bit11(k)=0, +1 when set.
// R6 change: non-temporal stores (output never re-read -> don't cache it;
// keeps the 128 MB input set resident in Infinity Cache) + 4096 blocks.

typedef unsigned int uint4v __attribute__((ext_vector_type(4)));
typedef float float4v __attribute__((ext_vector_type(4)));

__device__ __forceinline__ unsigned f2bf(float f) {
    // round-to-nearest-even float32 -> bf16 (inputs are finite normals)
    unsigned u = __float_as_uint(f);
    return (u + 0x7FFFu + ((u >> 16) & 1u)) >> 16;
}

__device__ __forceinline__ unsigned pack2(float lo, float hi) {
    return f2bf(lo) | (f2bf(hi) << 16);   // lo at lower address
}

__global__ __launch_bounds__(256) void ygate_kernel(
    const float4v* __restrict__ a4,   // d_in[0]
    const float4v* __restrict__ b4,   // d_in[1]
    uint4v* __restrict__ out4, int n8 /* = N/8 */) {
    int stride = gridDim.x * blockDim.x;
    for (int t = blockIdx.x * blockDim.x + threadIdx.x; t < n8; t += stride) {
        int f  = t << 1;        // first float4 index (complex base k = 8t)
        int jf = f ^ 512;       // partner: (k^2048)/4 = f ^ 512
        float4v a0 = a4[jf];
        float4v a1 = a4[jf + 1];
        float4v b0 = b4[jf];
        float4v b1 = b4[jf + 1];
        float s = ((t >> 8) & 1) ? 1.0f : -1.0f;   // bit 11 of k; wave-uniform
        uint4v o0, o1;
        o0.x = pack2( s * a0.x, -s * b0.x);
        o0.y = pack2( s * a0.y, -s * b0.y);
        o0.z = pack2( s * a0.z, -s * b0.z);
        o0.w = pack2( s * a0.w, -s * b0.w);
        o1.x = pack2( s * a1.x, -s * b1.x);
        o1.y = pack2( s * a1.y, -s * b1.y);
        o1.z = pack2( s * a1.z, -s * b1.z);
        o1.w = pack2( s * a1.w, -s * b1.w);
        __builtin_nontemporal_store(o0, &out4[f]);      // stream past L2/L3
        __builtin_nontemporal_store(o1, &out4[f + 1]);
    }
}

extern "C" void kernel_launch(void* const* d_in, const int* in_sizes, int n_in,
                              void* d_out, int out_size, void* d_ws, size_t ws_size,
                              hipStream_t stream) {
    const float4v* a4 = (const float4v*)d_in[0];
    const float4v* b4 = (const float4v*)d_in[1];
    uint4v* out4 = (uint4v*)d_out;
    int n  = in_sizes[0];      // 2^24 complex elements
    int n8 = n >> 3;           // 8 complex elems per thread-iteration
    ygate_kernel<<<4096, 256, 0, stream>>>(a4, b4, out4, n8);
}

// Round 7
// 33.611 us; speedup vs baseline: 1.0826x; 1.0826x over previous
//
#include <hip/hip_runtime.h>
#include <hip/hip_bf16.h>

// Y-gate on qubit INDEX=12 of a D=2, N=2^24 state vector.
// Partner index: j = k ^ 2048 (bit 11 = target-qubit bit).
// Output: bf16, interleaved pairs, 2^25 values total.
// Harness conventions (established empirically, r5 PASSED, absmax=1 ulp):
//   even slot[k] = s*A[j], odd slot[k] = -s*B[j]  with A=d_in[0], B=d_in[1],
//   s = -1 when bit11(k)=0, +1 when set.
// R7: revert nt stores (r6: WRITE_SIZE +13%, dur +2.3us — write-combining
// in L2 beats streaming). Drop grid-stride loop: 8192 blocks, 1 iter/thread,
// to attack the latency/issue bound (HBM only at 3.85 TB/s, not saturated).

typedef unsigned int uint4v __attribute__((ext_vector_type(4)));
typedef float float4v __attribute__((ext_vector_type(4)));

__device__ __forceinline__ unsigned f2bf(float f) {
    // round-to-nearest-even float32 -> bf16 (inputs are finite normals)
    unsigned u = __float_as_uint(f);
    return (u + 0x7FFFu + ((u >> 16) & 1u)) >> 16;
}

__device__ __forceinline__ unsigned pack2(float lo, float hi) {
    return f2bf(lo) | (f2bf(hi) << 16);   // lo at lower address
}

__global__ __launch_bounds__(256) void ygate_kernel(
    const float4v* __restrict__ a4,   // d_in[0]
    const float4v* __restrict__ b4,   // d_in[1]
    uint4v* __restrict__ out4) {
    int t  = blockIdx.x * blockDim.x + threadIdx.x;  // one iter per thread
    int f  = t << 1;        // first float4 index (complex base k = 8t)
    int jf = f ^ 512;       // partner: (k^2048)/4 = f ^ 512
    float4v a0 = a4[jf];
    float4v a1 = a4[jf + 1];
    float4v b0 = b4[jf];
    float4v b1 = b4[jf + 1];
    float s = ((t >> 8) & 1) ? 1.0f : -1.0f;   // bit 11 of k; wave-uniform
    uint4v o0, o1;
    o0.x = pack2( s * a0.x, -s * b0.x);
    o0.y = pack2( s * a0.y, -s * b0.y);
    o0.z = pack2( s * a0.z, -s * b0.z);
    o0.w = pack2( s * a0.w, -s * b0.w);
    o1.x = pack2( s * a1.x, -s * b1.x);
    o1.y = pack2( s * a1.y, -s * b1.y);
    o1.z = pack2( s * a1.z, -s * b1.z);
    o1.w = pack2( s * a1.w, -s * b1.w);
    out4[f]     = o0;       // uint4 = 4 pairs (lo at even slot)
    out4[f + 1] = o1;
}

extern "C" void kernel_launch(void* const* d_in, const int* in_sizes, int n_in,
                              void* d_out, int out_size, void* d_ws, size_t ws_size,
                              hipStream_t stream) {
    const float4v* a4 = (const float4v*)d_in[0];
    const float4v* b4 = (const float4v*)d_in[1];
    uint4v* out4 = (uint4v*)d_out;
    int n  = in_sizes[0];          // 2^24 complex elements
    int n8 = n >> 3;               // 8 complex elems per thread
    int grid = n8 / 256;           // = 8192 blocks, exact cover
    ygate_kernel<<<grid, 256, 0, stream>>>(a4, b4, out4);
}